// Round 3
// baseline (502.340 us; speedup 1.0000x reference)
//
#include <hip/hip_runtime.h>

#define NB 16
#define NN 512
#define NP 513   // N+1
#define NM 511   // N-1
#define CFLc 0.5f

#define SE (NP*NP)     // per-batch E
#define SHX (NM*NN)    // per-batch Hx (511 rows x 512 cols)
#define SHY (NN*NM)    // per-batch Hy (512 rows x 511 cols)

// workspace layout (floats):
//  A  : amper row-edge partials   [NB][NCH][6][512]   (written K1, read K2)
//  F  : faraday hy-edge partials  [NB][NCH][4][512]   (written K2, read next K1 / final fix)
//  SEs: stash of RAW E strip rows [NB][6][NP]         (written K1, read K2)
//  SHs: stash of RAW Hy strip rows[NB][4][NM]         (written K2, read next K1 / final fix)
#define NCH 8
#define OFF_A 0
#define SZ_A (NB*NCH*6*512)
#define OFF_F (OFF_A + SZ_A)
#define SZ_F (NB*NCH*4*512)
#define OFF_SE (OFF_F + SZ_F)
#define SZ_SE (NB*6*NP)
#define OFF_SH (OFF_SE + SZ_SE)
#define SZ_SH (NB*4*NM)
// total = 393216+262144+49248+32704 = 737312 floats = 2.95 MB (< prior 3.34 MB use)

__device__ __forceinline__ float dot4(float4 a, float4 b) {
    return a.x*b.x + a.y*b.y + a.z*b.z + a.w*b.w;
}

// load arr4[mb-1 .. mb+3] with zero-fill outside valid range [0,509]
__device__ __forceinline__ void ld5(const float* __restrict__ a, int mb, float4* cr) {
    const float4* a4 = (const float4*)a;
    #pragma unroll
    for (int t = 0; t < 5; t++) {
        int idx = mb - 1 + t;
        if (idx >= 0 && idx <= 509) cr[t] = a4[idx];
        else cr[t] = make_float4(0.f, 0.f, 0.f, 0.f);
    }
}

// ==================================================================
// K1:  AE-B (row-edge partials from Hx -> A region, 8 chunks)
//   || amper stencil (LDS staged, fused column-strip dots,
//      Hy strip rows read from stash+F correction when fix=1,
//      raw E strip rows -> global AND stash)
//   || fixer blocks: write CORRECTED Hy strip rows to global (fix=1)
// ==================================================================
__global__ __launch_bounds__(512, 4) void k_step1(
    const float* __restrict__ E, const float* __restrict__ Hx, const float* __restrict__ Hy,
    const float* __restrict__ beta, const float* __restrict__ delta,
    const float* __restrict__ fb, const float* __restrict__ fd, const float* __restrict__ fy,
    const float* __restrict__ kf, const float* __restrict__ kb,
    const float* __restrict__ fu, const float* __restrict__ fdn,
    float* __restrict__ ws, float* __restrict__ Eout,
    float* __restrict__ Hyfix, int fix)
{
    __shared__ float s_hy[7][512];
    __shared__ float s_hx[6][512];
    __shared__ float s_strip[8][6];
    __shared__ float gsm[12];

    int bid = blockIdx.x;
    int tid = threadIdx.x;

    if (bid < 128) {
        // ---------- AE part B: column reductions over Hx (8 chunks of 64) ----------
        int b = bid >> 3;
        int chunk = bid & 7;
        int j = tid;
        if (j > 508) return;
        int p0 = chunk * 64;
        int p1 = min(510, p0 + 64);
        const float* Hxb = Hx + (size_t)b*SHX;
        float akf0=0,akf1=0,akb0=0,akb1=0,afu0=0,afu1=0,afd0=0,afd1=0;
        float r0v[4], r1v[4];
        #pragma unroll
        for (int q = 0; q < 4; q++) r0v[q] = Hxb[(size_t)p0*NN + j + q];
        for (int p = p0; p < p1; p++) {
            #pragma unroll
            for (int q = 0; q < 4; q++) r1v[q] = Hxb[(size_t)(p+1)*NN + j + q];
            #pragma unroll
            for (int q = 0; q < 4; q++) {
                float ckf = kf[p*4+q], ckb = kb[p*4+q], cfu = fu[p*4+q], cfd = fdn[p*4+q];
                akf0 += r0v[q]*ckf; akf1 += r1v[q]*ckf;
                akb0 += r0v[q]*ckb; akb1 += r1v[q]*ckb;
                afu0 += r0v[q]*cfu; afu1 += r1v[q]*cfu;
                afd0 += r0v[q]*cfd; afd1 += r1v[q]*cfd;
            }
            #pragma unroll
            for (int q = 0; q < 4; q++) r0v[q] = r1v[q];
        }
        float* o = ws + OFF_A + (((size_t)b*NCH + chunk)*6)*512 + j;
        o[0*512] = akf0;
        o[1*512] = akf1 + afu0;
        o[2*512] = afu1;
        o[3*512] = afd0;
        o[4*512] = afd1 + akb0;
        o[5*512] = akb1;
        return;
    }

    if (bid >= 2192) {
        // ---------- fixer: corrected Hy strip rows {0,1,510,511} ----------
        if (!fix) return;
        int b = bid - 2192;
        int c = tid;
        if (c > 510) return;
        #pragma unroll
        for (int slot = 0; slot < 4; slot++) {
            int r = (slot < 2) ? slot : 508 + slot;
            float s = 0.f;
            #pragma unroll
            for (int ch = 0; ch < NCH; ch++)
                s += ws[OFF_F + (((size_t)b*NCH + ch)*4 + slot)*512 + c];
            Hyfix[(size_t)b*SHY + (size_t)r*NM + c] =
                ws[OFF_SH + ((size_t)b*4 + slot)*NM + c] + CFLc*s;
        }
        return;
    }

    // ---------- amper stencil (rows r0..r0+3, full width) ----------
    int wrk = bid - 128;                      // 0..2063
    wrk = (wrk & 7) * 258 + (wrk >> 3);       // bijective XCD-chunk swizzle (2064 = 8*258)
    int rg = wrk >> 4;                        // 0..128
    int b  = wrk & 15;
    int r0 = rg * 4;

    const float* Eb  = E  + (size_t)b*SE;
    const float* Hxb = Hx + (size_t)b*SHX;
    const float* Hyb = Hy + (size_t)b*SHY;
    int c = tid;                              // 0..511 (col 512 handled by thread 511)

    if (tid < 12) gsm[tid] = beta[0]*fb[tid] + delta[0]*fd[tid] + fy[tid];
    #pragma unroll
    for (int k = 0; k < 7; k++) {
        int rm = min(max(r0-2+k, 0), 511);
        int cc = min(c, 510);
        float v;
        if (fix && (rm <= 1 || rm >= 510)) {
            // Hy strip row: raw stash + faraday strip correction
            int slot = (rm <= 1) ? rm : rm - 508;
            float s = 0.f;
            #pragma unroll
            for (int ch = 0; ch < NCH; ch++)
                s += ws[OFF_F + (((size_t)b*NCH + ch)*4 + slot)*512 + cc];
            v = ws[OFF_SH + ((size_t)b*4 + slot)*NM + cc] + CFLc*s;
        } else {
            v = Hyb[(size_t)rm*NM + cc];
        }
        s_hy[k][c] = v;
    }
    #pragma unroll
    for (int k = 0; k < 6; k++) {
        int rm = min(max(r0-2+k, 0), 510);
        s_hx[k][c] = Hxb[(size_t)rm*NN + c];
    }
    __syncthreads();

    // ----- fused column-strip dots (from s_hy) -----
    {
        int w = tid >> 6, lane = tid & 63;
        int jj = w >> 1;
        int ii = r0 + jj - 2;
        if (ii >= 0 && ii <= 508) {
            int h = w & 1;
            int mb = h*256 + lane*4;
            float4 hv0 = *(const float4*)&s_hy[jj+0][mb];
            float4 hv1 = *(const float4*)&s_hy[jj+1][mb];
            float4 hv2 = *(const float4*)&s_hy[jj+2][mb];
            float4 hv3 = *(const float4*)&s_hy[jj+3][mb];
            float4 hc0 = make_float4(hv0.x, hv1.x, hv2.x, hv3.x);
            float4 hc1 = make_float4(hv0.y, hv1.y, hv2.y, hv3.y);
            float4 hc2 = make_float4(hv0.z, hv1.z, hv2.z, hv3.z);
            float4 hc3 = make_float4(hv0.w, hv1.w, hv2.w, hv3.w);
            float4 cr[5];
            ld5(kf, mb, cr);
            float pkf0 = dot4(hc0,cr[1]) + dot4(hc1,cr[2]) + dot4(hc2,cr[3]) + dot4(hc3,cr[4]);
            float pkf1 = dot4(hc0,cr[0]) + dot4(hc1,cr[1]) + dot4(hc2,cr[2]) + dot4(hc3,cr[3]);
            ld5(fu, mb, cr);
            float pfu0 = dot4(hc0,cr[1]) + dot4(hc1,cr[2]) + dot4(hc2,cr[3]) + dot4(hc3,cr[4]);
            float pfu1 = dot4(hc0,cr[0]) + dot4(hc1,cr[1]) + dot4(hc2,cr[2]) + dot4(hc3,cr[3]);
            ld5(fdn, mb, cr);
            float pfd0 = dot4(hc0,cr[1]) + dot4(hc1,cr[2]) + dot4(hc2,cr[3]) + dot4(hc3,cr[4]);
            float pfd1 = dot4(hc0,cr[0]) + dot4(hc1,cr[1]) + dot4(hc2,cr[2]) + dot4(hc3,cr[3]);
            ld5(kb, mb, cr);
            float pkb0 = dot4(hc0,cr[1]) + dot4(hc1,cr[2]) + dot4(hc2,cr[3]) + dot4(hc3,cr[4]);
            float pkb1 = dot4(hc0,cr[0]) + dot4(hc1,cr[1]) + dot4(hc2,cr[2]) + dot4(hc3,cr[3]);
            float v0 = pkf0;
            float v1 = pkf1 + pfu0;
            float v2 = pfu1;
            float v3 = pfd0;
            float v4 = pfd1 + pkb0;
            float v5 = pkb1;
            #pragma unroll
            for (int off = 32; off > 0; off >>= 1) {
                v0 += __shfl_down(v0, off);
                v1 += __shfl_down(v1, off);
                v2 += __shfl_down(v2, off);
                v3 += __shfl_down(v3, off);
                v4 += __shfl_down(v4, off);
                v5 += __shfl_down(v5, off);
            }
            if (lane == 0) {
                s_strip[w][0]=v0; s_strip[w][1]=v1; s_strip[w][2]=v2;
                s_strip[w][3]=v3; s_strip[w][4]=v4; s_strip[w][5]=v5;
            }
        }
    }
    __syncthreads();

    float g[12];
    #pragma unroll
    for (int i = 0; i < 12; i++) g[i] = gsm[i];

    int cy0 = min(max(c-2,0),510), cy1 = min(max(c-1,0),510), cy2 = min(c,510);
    int cx0 = max(c-2,0), cx1 = max(c-1,0), cx3 = min(c+1,511);
    float hyv[7][3];
    #pragma unroll
    for (int k = 0; k < 7; k++) {
        hyv[k][0]=s_hy[k][cy0]; hyv[k][1]=s_hy[k][cy1]; hyv[k][2]=s_hy[k][cy2];
    }
    float hxv[6][4];
    #pragma unroll
    for (int k = 0; k < 6; k++) {
        hxv[k][0]=s_hx[k][cx0]; hxv[k][1]=s_hx[k][cx1]; hxv[k][2]=s_hx[k][c]; hxv[k][3]=s_hx[k][cx3];
    }

    bool cint = (c >= 2 && c <= 510);
    int cslot = (c==0)?0:(c==1)?1:(c==2)?2:(c==510)?3:(c==511)?4:-1;
    float* Eo = Eout + (size_t)b*SE;

    #pragma unroll
    for (int j2 = 0; j2 < 4; j2++) {
        int r = r0 + j2;
        if (r > 512) break;            // wave-uniform
        float v = Eb[(size_t)r*NP + c];
        bool rint = (r >= 2 && r <= 510);
        if (rint && cint) {
            float s1 = 0.f, s2 = 0.f;
            #pragma unroll
            for (int p = 0; p < 4; p++)
                s1 += g[p]*hyv[j2+p][0] + g[4+p]*hyv[j2+p][1] + g[8+p]*hyv[j2+p][2];
            #pragma unroll
            for (int p = 0; p < 3; p++)
                s2 += g[p*4+0]*hxv[j2+p][0] + g[p*4+1]*hxv[j2+p][1]
                    + g[p*4+2]*hxv[j2+p][2] + g[p*4+3]*hxv[j2+p][3];
            v += CFLc * (s1 - s2);
        }
        if (rint && cslot >= 0)
            v += CFLc * (s_strip[2*j2][cslot] + s_strip[2*j2+1][cslot]);
        Eo[(size_t)r*NP + c] = v;
        bool rstrip = (r <= 2 || r >= 510);
        int rslot = (r <= 2) ? r : r - 507;
        if (rstrip)
            ws[OFF_SE + ((size_t)b*6 + rslot)*NP + c] = v;   // raw stash
        if (c == 511) {                // column 512 (slot 5, no interior/row-strip term)
            float v2 = Eb[(size_t)r*NP + 512];
            if (rint) v2 += CFLc * (s_strip[2*j2][5] + s_strip[2*j2+1][5]);
            Eo[(size_t)r*NP + 512] = v2;
            if (rstrip)
                ws[OFF_SE + ((size_t)b*6 + rslot)*NP + 512] = v2;
        }
    }
}

// ==================================================================
// K2:  FE-B (col partials over E -> F region, 8 chunks; strip rows of E
//      read via stash+A correction in LDS)
//   || merged faraday stencil: ONE block type stages 7 E rows and
//      computes BOTH Hx (fused kef/keb strips) and Hy rows;
//      raw Hy strip rows -> global AND stash
//   || fixer blocks: write CORRECTED E strip rows to global
// ==================================================================
__global__ __launch_bounds__(512, 4) void k_step2(
    const float* __restrict__ E, const float* __restrict__ Hx, const float* __restrict__ Hy,
    const float* __restrict__ beta, const float* __restrict__ delta,
    const float* __restrict__ fb, const float* __restrict__ fd, const float* __restrict__ fy,
    const float* __restrict__ kef, const float* __restrict__ keb,
    float* __restrict__ ws, float* __restrict__ Hxout, float* __restrict__ Hyout,
    float* __restrict__ Efix)
{
    __shared__ float s_e[7][520];
    __shared__ float s_fix[3][NP];
    __shared__ float s_strip2[8][4];
    __shared__ float gsm[12];

    int bid = blockIdx.x;
    int tid = threadIdx.x;

    if (bid < 128) {
        // ---------- FE part B: column reductions over E (8 chunks of 64) ----------
        int b = bid >> 3, chunk = bid & 7;
        const float* Eb = E + (size_t)b*SE;
        bool bnd = (chunk == 0 || chunk == 7);
        int rbase = (chunk == 0) ? 0 : 510;
        if (bnd) {
            int sbase = (chunk == 0) ? 0 : 3;
            for (int t = tid; t < 3*NP; t += 512) {
                int sr = t / NP, cc = t - sr*NP;
                int slot = sbase + sr;
                float v = ws[OFF_SE + ((size_t)b*6 + slot)*NP + cc];
                if (cc >= 2 && cc <= 510) {
                    float s = 0.f;
                    #pragma unroll
                    for (int ch = 0; ch < NCH; ch++)
                        s += ws[OFF_A + (((size_t)b*NCH + ch)*6 + slot)*512 + (cc-2)];
                    v -= CFLc * s;
                }
                s_fix[sr][cc] = v;
            }
            __syncthreads();
        }
        int c = tid;
        if (c > 510) return;
        int p0 = chunk*64, p1 = p0 + 64;
        auto ldE = [&](int rr, int col) -> float {
            if (bnd) {
                unsigned d = (unsigned)(rr - rbase);
                if (d < 3u) return s_fix[d][col];
            }
            return Eb[(size_t)rr*NP + col];
        };
        float af0=0, af1=0, ab0=0, ab1=0;
        float r0v[3], r1v[3];
        #pragma unroll
        for (int q = 0; q < 3; q++) r0v[q] = ldE(p0, c + q);
        for (int p = p0; p < p1; p++) {
            #pragma unroll
            for (int q = 0; q < 3; q++) r1v[q] = ldE(p+1, c + q);
            float cf0 = kef[p], cf1 = kef[512+p], cf2 = kef[1024+p];
            float cb0 = keb[p], cb1 = keb[512+p], cb2 = keb[1024+p];
            af0 += r0v[0]*cf0 + r0v[1]*cf1 + r0v[2]*cf2;
            af1 += r1v[0]*cf0 + r1v[1]*cf1 + r1v[2]*cf2;
            ab0 += r0v[0]*cb0 + r0v[1]*cb1 + r0v[2]*cb2;
            ab1 += r1v[0]*cb0 + r1v[1]*cb1 + r1v[2]*cb2;
            r0v[0]=r1v[0]; r0v[1]=r1v[1]; r0v[2]=r1v[2];
        }
        float* o = ws + OFF_F + (((size_t)b*NCH + chunk)*4)*512 + c;
        o[0*512] = af0; o[1*512] = af1; o[2*512] = ab0; o[3*512] = ab1;
        return;
    }

    if (bid >= 2176) {
        // ---------- fixer: corrected E strip rows {0,1,2,510,511,512}, cols [2,510] ----------
        int b = bid - 2176;
        int c = tid;
        if (c < 2 || c > 510) return;
        #pragma unroll
        for (int slot = 0; slot < 6; slot++) {
            int r = (slot < 3) ? slot : 507 + slot;
            float s = 0.f;
            #pragma unroll
            for (int ch = 0; ch < NCH; ch++)
                s += ws[OFF_A + (((size_t)b*NCH + ch)*6 + slot)*512 + (c-2)];
            Efix[(size_t)b*SE + (size_t)r*NP + c] =
                ws[OFF_SE + ((size_t)b*6 + slot)*NP + c] - CFLc*s;
        }
        return;
    }

    // ---------- merged faraday stencil: Hx rows r0..r0+3 AND Hy rows r0..r0+3 ----------
    if (tid < 12) gsm[tid] = beta[0]*fb[tid] + delta[0]*fd[tid] + fy[tid];
    int wrk = bid - 128;                   // 0..2047
    wrk = (wrk & 7)*256 + (wrk >> 3);      // bijective XCD-chunk swizzle
    int y = wrk >> 4, b = wrk & 15;
    int r0 = y*4;
    const float* Eb = E + (size_t)b*SE;
    int c = tid;

    // stage E rows r0-1 .. r0+5 (strip rows via stash + A correction)
    #pragma unroll
    for (int k = 0; k < 7; k++) {
        int rm = min(max(r0-1+k, 0), 512);
        bool strip = (rm <= 2 || rm >= 510);
        int slot = (rm <= 2) ? rm : rm - 507;
        float v;
        if (strip) {
            v = ws[OFF_SE + ((size_t)b*6 + slot)*NP + c];
            if (c >= 2 && c <= 510) {
                float s = 0.f;
                #pragma unroll
                for (int ch = 0; ch < NCH; ch++)
                    s += ws[OFF_A + (((size_t)b*NCH + ch)*6 + slot)*512 + (c-2)];
                v -= CFLc * s;
            }
        } else {
            v = Eb[(size_t)rm*NP + c];
        }
        s_e[k][c] = v;
        if (c == 511) {
            float v2 = strip ? ws[OFF_SE + ((size_t)b*6 + slot)*NP + 512]
                             : Eb[(size_t)rm*NP + 512];
            s_e[k][512] = v2;
        }
    }
    __syncthreads();

    // fused kef/keb strips for Hx (s_e row k = E row r0-1+k => +1 shift)
    {
        int w = tid >> 6, lane = tid & 63;
        int jj = w >> 1, h = w & 1;
        int rr = r0 + jj;
        if (rr <= 510) {
            int mb = h*256 + lane*4;
            int q4 = mb >> 2;
            float4 e0 = *(const float4*)&s_e[jj+1][mb];
            float4 e1 = *(const float4*)&s_e[jj+2][mb];
            float4 e2 = *(const float4*)&s_e[jj+3][mb];
            const float4* kef4 = (const float4*)kef;
            const float4* keb4 = (const float4*)keb;
            float4 f0 = kef4[q4], f1 = kef4[128+q4], f2 = kef4[256+q4];
            float4 b0 = keb4[q4], b1 = keb4[128+q4], b2 = keb4[256+q4];
            float af0 = dot4(e0,f0) + dot4(e1,f1) + dot4(e2,f2);
            float ab0 = dot4(e0,b0) + dot4(e1,b1) + dot4(e2,b2);
            float pw0 = (mb >= 1) ? kef[mb-1]      : 0.f;
            float pw1 = (mb >= 1) ? kef[512+mb-1]  : 0.f;
            float pw2 = (mb >= 1) ? kef[1024+mb-1] : 0.f;
            float af1 = dot4(e0, make_float4(pw0, f0.x, f0.y, f0.z))
                      + dot4(e1, make_float4(pw1, f1.x, f1.y, f1.z))
                      + dot4(e2, make_float4(pw2, f2.x, f2.y, f2.z));
            pw0 = (mb >= 1) ? keb[mb-1]      : 0.f;
            pw1 = (mb >= 1) ? keb[512+mb-1]  : 0.f;
            pw2 = (mb >= 1) ? keb[1024+mb-1] : 0.f;
            float ab1 = dot4(e0, make_float4(pw0, b0.x, b0.y, b0.z))
                      + dot4(e1, make_float4(pw1, b1.x, b1.y, b1.z))
                      + dot4(e2, make_float4(pw2, b2.x, b2.y, b2.z));
            // m'=512 term of the shifted outputs: E col 512 x coeff idx 511
            if (mb == 508) {
                float e512_0 = s_e[jj+1][512];
                float e512_1 = s_e[jj+2][512];
                float e512_2 = s_e[jj+3][512];
                af1 += e512_0*kef[511] + e512_1*kef[1023] + e512_2*kef[1535];
                ab1 += e512_0*keb[511] + e512_1*keb[1023] + e512_2*keb[1535];
            }
            #pragma unroll
            for (int off = 32; off > 0; off >>= 1) {
                af0 += __shfl_down(af0, off);
                af1 += __shfl_down(af1, off);
                ab0 += __shfl_down(ab0, off);
                ab1 += __shfl_down(ab1, off);
            }
            if (lane == 0) {
                s_strip2[w][0]=af0; s_strip2[w][1]=af1;
                s_strip2[w][2]=ab0; s_strip2[w][3]=ab1;
            }
        }
    }
    __syncthreads();

    // ---- Hx part (cols 0..511) ----
    {
        float g[12];
        #pragma unroll
        for (int i = 0; i < 12; i++) g[i] = gsm[i];
        int c0 = max(c-1,0), c2i = min(c+1,512), c3i = min(c+2,512);
        float ev[6][4];
        #pragma unroll
        for (int k = 0; k < 6; k++) {
            ev[k][0]=s_e[k+1][c0]; ev[k][1]=s_e[k+1][c];
            ev[k][2]=s_e[k+1][c2i]; ev[k][3]=s_e[k+1][c3i];
        }
        bool cint = (c >= 1 && c <= 510);
        int slot = (c==0)?0:(c==1)?1:(c==510)?2:(c==511)?3:-1;
        const float* Hxb = Hx + (size_t)b*SHX;
        float* Ho = Hxout + (size_t)b*SHX;
        #pragma unroll
        for (int j2 = 0; j2 < 4; j2++) {
            int r = r0 + j2;
            if (r > 510) break;        // uniform
            float v = Hxb[(size_t)r*NN + c];
            if (cint) {
                float s = 0.f;
                #pragma unroll
                for (int p = 0; p < 3; p++)
                    s += g[p*4+0]*ev[j2+p][0] + g[p*4+1]*ev[j2+p][1]
                       + g[p*4+2]*ev[j2+p][2] + g[p*4+3]*ev[j2+p][3];
                v -= CFLc * s;
            }
            if (slot >= 0)
                v -= CFLc * (s_strip2[2*j2][slot] + s_strip2[2*j2+1][slot]);
            Ho[(size_t)r*NN + c] = v;
        }
    }

    // ---- Hy part (cols 0..510) ----
    if (c <= 510) {
        float g[12];
        #pragma unroll
        for (int i = 0; i < 12; i++) g[i] = gsm[i];
        float ev[7][3];
        #pragma unroll
        for (int k = 0; k < 7; k++) {
            ev[k][0]=s_e[k][c]; ev[k][1]=s_e[k][c+1]; ev[k][2]=s_e[k][c+2];
        }
        const float* Hyb = Hy + (size_t)b*SHY;
        float* Ho = Hyout + (size_t)b*SHY;
        #pragma unroll
        for (int j2 = 0; j2 < 4; j2++) {
            int r = r0 + j2;               // <= 511 always
            float v = Hyb[(size_t)r*NM + c];
            if (r >= 1 && r <= 510) {
                float s = 0.f;
                #pragma unroll
                for (int p = 0; p < 4; p++)
                    s += g[p]*ev[j2+p][0] + g[4+p]*ev[j2+p][1] + g[8+p]*ev[j2+p][2];
                v += CFLc * s;
            }
            Ho[(size_t)r*NM + c] = v;      // raw; strips corrected by next K1 / final fix
            if (r <= 1 || r >= 510)
                ws[OFF_SH + ((size_t)b*4 + ((r<=1)?r:r-508))*NM + c] = v;  // raw stash
        }
    }
}

// ==================================================================
// final: corrected Hy4 strip rows {0,1,510,511}
// ==================================================================
__global__ __launch_bounds__(512) void k_fix_hy_final(
    const float* __restrict__ ws, float* __restrict__ Hyout)
{
    int b = blockIdx.x;
    int c = threadIdx.x;
    if (c > 510) return;
    #pragma unroll
    for (int slot = 0; slot < 4; slot++) {
        int r = (slot < 2) ? slot : 508 + slot;
        float s = 0.f;
        #pragma unroll
        for (int ch = 0; ch < NCH; ch++)
            s += ws[OFF_F + (((size_t)b*NCH + ch)*4 + slot)*512 + c];
        Hyout[(size_t)b*SHY + (size_t)r*NM + c] =
            ws[OFF_SH + ((size_t)b*4 + slot)*NM + c] + CFLc*s;
    }
}

// ---------------- driver ----------------

static void run_step(const float* Ein, const float* Hxin, const float* Hyin,
                     float* Eout, float* Hxout, float* Hyout, float* ws,
                     const float* beta, const float* delta,
                     const float* fb, const float* fd, const float* fy,
                     const float* kf, const float* kb, const float* fu, const float* fdn,
                     const float* kef, const float* keb,
                     float* HyfixTarget, int fix, hipStream_t stream)
{
    dim3 blk(512);
    k_step1<<<dim3(2208), blk, 0, stream>>>(Ein, Hxin, Hyin, beta, delta,
        fb, fd, fy, kf, kb, fu, fdn, ws, Eout, HyfixTarget, fix);
    k_step2<<<dim3(2192), blk, 0, stream>>>(Eout, Hxin, Hyin, beta, delta,
        fb, fd, fy, kef, keb, ws, Hxout, Hyout, Eout);
}

extern "C" void kernel_launch(void* const* d_in, const int* in_sizes, int n_in,
                              void* d_out, int out_size, void* d_ws, size_t ws_size,
                              hipStream_t stream)
{
    const float* E1   = (const float*)d_in[0];
    const float* Hx1  = (const float*)d_in[1];
    const float* Hy1  = (const float*)d_in[2];
    const float* beta = (const float*)d_in[9];
    const float* delta= (const float*)d_in[10];
    const float* fb   = (const float*)d_in[11];
    const float* fd   = (const float*)d_in[12];
    const float* fy   = (const float*)d_in[13];
    const float* kf   = (const float*)d_in[14];
    const float* kb   = (const float*)d_in[15];
    const float* fu   = (const float*)d_in[16];
    const float* fdn  = (const float*)d_in[17];
    const float* kef  = (const float*)d_in[18];
    const float* keb  = (const float*)d_in[19];

    float* out = (float*)d_out;
    float* ws  = (float*)d_ws;   // needs ~2.95 MB
    size_t SEa = (size_t)NB * SE;
    size_t SHa = (size_t)NB * SHX;   // == NB*SHY
    float* E2  = out;
    float* Hx2 = E2  + SEa;
    float* Hy2 = Hx2 + SHa;
    float* E3  = Hy2 + SHa;
    float* Hx3 = E3  + SEa;
    float* Hy3 = Hx3 + SHa;
    float* E4  = Hy3 + SHa;
    float* Hx4 = E4  + SEa;
    float* Hy4 = Hx4 + SHa;

    run_step(E1, Hx1, Hy1, E2, Hx2, Hy2, ws, beta, delta, fb, fd, fy,
             kf, kb, fu, fdn, kef, keb, nullptr, 0, stream);
    run_step(E2, Hx2, Hy2, E3, Hx3, Hy3, ws, beta, delta, fb, fd, fy,
             kf, kb, fu, fdn, kef, keb, Hy2, 1, stream);
    run_step(E3, Hx3, Hy3, E4, Hx4, Hy4, ws, beta, delta, fb, fd, fy,
             kf, kb, fu, fdn, kef, keb, Hy3, 1, stream);
    k_fix_hy_final<<<dim3(16), dim3(512), 0, stream>>>(ws, Hy4);
}